// Round 1
// baseline (1507.274 us; speedup 1.0000x reference)
//
#include <hip/hip_runtime.h>

// LSTM: B=256, T=512, I=256, H=128 (4H=512 gates), then MLP 128->64->32->4.
// Structure:
//   gemm_gx_kernel : gx[t_l*256+b][g] = x[b][t0+t_l][:] . W_ih[g][:] + (b_ih+b_hh)[g]
//                    (classic 128x128 LDS-tiled fp32 GEMM, K-slice 32)
//   lstm_chunk_kernel : 1 block per batch row; W_hh row-per-thread in VGPRs;
//                       h broadcast from LDS; 64 timesteps per launch
//   head_kernel : tiny MLP per row
// Chunked over T (8 chunks of 64) so workspace = 33.5 MB gx + 256 KB h/c state.

#define TC    64
#define NCHUNK 8
#define BATCH 256
#define TSEQ  512
#define ISZ   256
#define HSZ   128
#define G4    512

__device__ __forceinline__ float sigmoidf_(float x) {
    return 1.0f / (1.0f + __expf(-x));
}
__device__ __forceinline__ float tanhf_(float x) {
    float e = __expf(2.0f * x);          // large |x| saturates correctly (inf -> 1, 0 -> -1)
    return 1.0f - 2.0f / (e + 1.0f);
}
__device__ __forceinline__ void fma4(float& a, const float4& w, const float4& h) {
    a += w.x * h.x; a += w.y * h.y; a += w.z * h.z; a += w.w * h.w;
}

// ---------------------------------------------------------------------------
// gx GEMM: M = TC*256 rows (m = t_l*256 + b), N = 512, K = 256, fp32.
// 128x128 tile per block, 256 threads, 8x8 micro-tile, K staged in slices of 32.
__global__ __launch_bounds__(256, 2) void gemm_gx_kernel(
    const float* __restrict__ x, const float* __restrict__ Wih,
    const float* __restrict__ bih, const float* __restrict__ bhh,
    float* __restrict__ gx, int t0)
{
    __shared__ __align__(16) float As[128 * 36];   // pad 32->36 floats/row
    __shared__ __align__(16) float Bs[128 * 36];
    const int tid   = threadIdx.x;
    const int mtile = blockIdx.x;          // 0..127
    const int ntile = blockIdx.y;          // 0..3
    const int tl = mtile >> 1;             // local timestep of this row-tile
    const int b0 = (mtile & 1) * 128;      // batch offset of this row-tile
    const int n0 = ntile * 128;
    const int tx = tid & 15;               // output-col group
    const int ty = tid >> 4;               // output-row group

    float acc[8][8];
#pragma unroll
    for (int i = 0; i < 8; ++i)
#pragma unroll
        for (int j = 0; j < 8; ++j) acc[i][j] = 0.0f;

    const int sf = tid & 7;                // float4 index within 32-wide K slice
    const int sr = tid >> 3;               // row base 0..31

    for (int ks = 0; ks < ISZ; ks += 32) {
#pragma unroll
        for (int u = 0; u < 4; ++u) {
            const int r = sr + u * 32;
            const float4 va = *(const float4*)(
                x + ((size_t)(b0 + r) * TSEQ + (size_t)(t0 + tl)) * ISZ + ks + sf * 4);
            *(float4*)(&As[r * 36 + sf * 4]) = va;
            const float4 vb = *(const float4*)(
                Wih + (size_t)(n0 + r) * ISZ + ks + sf * 4);
            *(float4*)(&Bs[r * 36 + sf * 4]) = vb;
        }
        __syncthreads();
#pragma unroll
        for (int kq = 0; kq < 8; ++kq) {
            float4 av[8], bv[8];
#pragma unroll
            for (int i = 0; i < 8; ++i)
                av[i] = *(const float4*)(&As[(ty * 8 + i) * 36 + kq * 4]);
#pragma unroll
            for (int j = 0; j < 8; ++j)
                bv[j] = *(const float4*)(&Bs[(tx + 16 * j) * 36 + kq * 4]);
#pragma unroll
            for (int i = 0; i < 8; ++i)
#pragma unroll
                for (int j = 0; j < 8; ++j)
                    fma4(acc[i][j], av[i], bv[j]);
        }
        __syncthreads();
    }

    const int m0 = mtile * 128;
#pragma unroll
    for (int j = 0; j < 8; ++j) {
        const int n = n0 + tx + 16 * j;
        const float bias = bih[n] + bhh[n];
#pragma unroll
        for (int i = 0; i < 8; ++i) {
            const int r = ty * 8 + i;
            gx[(size_t)(m0 + r) * G4 + n] = acc[i][j] + bias;
        }
    }
}

// ---------------------------------------------------------------------------
// Recurrence: grid = 256 blocks (one batch row each), 512 threads (one gate each).
// Thread g holds W_hh[g][0..127] in 128 VGPRs; h lives in LDS (broadcast reads).
__global__ __launch_bounds__(512, 2) void lstm_chunk_kernel(
    const float* __restrict__ gx, const float* __restrict__ Whh,
    float* __restrict__ hc, int first)
{
    __shared__ __align__(16) float h_s[HSZ];
    __shared__ float gates_s[G4];
    const int b = blockIdx.x;
    const int g = threadIdx.x;

    float4 W[32];
    const float4* wrow = (const float4*)(Whh + (size_t)g * HSZ);
#pragma unroll
    for (int kk = 0; kk < 32; ++kk) W[kk] = wrow[kk];

    float c = 0.0f;
    if (g < HSZ) {
        float h0 = 0.0f;
        if (!first) {
            h0 = hc[b * HSZ + g];
            c  = hc[BATCH * HSZ + b * HSZ + g];
        }
        h_s[g] = h0;
    }
    __syncthreads();

    for (int t = 0; t < TC; ++t) {
        const float gv = gx[((size_t)t * BATCH + b) * G4 + g];   // precomputed x-part + bias
        float a0 = 0.f, a1 = 0.f, a2 = 0.f, a3 = 0.f;            // 4 chains for ILP
        const float4* h4 = (const float4*)h_s;
#pragma unroll
        for (int kk = 0; kk < 32; kk += 4) {
            const float4 h0v = h4[kk + 0];
            const float4 h1v = h4[kk + 1];
            const float4 h2v = h4[kk + 2];
            const float4 h3v = h4[kk + 3];
            fma4(a0, W[kk + 0], h0v);
            fma4(a1, W[kk + 1], h1v);
            fma4(a2, W[kk + 2], h2v);
            fma4(a3, W[kk + 3], h3v);
        }
        gates_s[g] = gv + ((a0 + a1) + (a2 + a3));
        __syncthreads();
        if (g < HSZ) {
            const float ig = sigmoidf_(gates_s[g]);
            const float fg = sigmoidf_(gates_s[HSZ + g]);
            const float gg = tanhf_(gates_s[2 * HSZ + g]);
            const float og = sigmoidf_(gates_s[3 * HSZ + g]);
            c = fg * c + ig * gg;
            h_s[g] = og * tanhf_(c);
        }
        __syncthreads();
    }

    if (g < HSZ) {
        hc[b * HSZ + g]               = h_s[g];
        hc[BATCH * HSZ + b * HSZ + g] = c;
    }
}

// ---------------------------------------------------------------------------
// MLP head: one block (64 threads) per batch row.
__global__ __launch_bounds__(64) void head_kernel(
    const float* __restrict__ hc,
    const float* __restrict__ W1, const float* __restrict__ b1,
    const float* __restrict__ W2, const float* __restrict__ b2,
    const float* __restrict__ W3, const float* __restrict__ b3,
    float* __restrict__ out)
{
    __shared__ float hs[HSZ];
    __shared__ float o1[64];
    __shared__ float o2[32];
    const int bidx = blockIdx.x;
    const int t = threadIdx.x;
    hs[t]      = hc[bidx * HSZ + t];
    hs[t + 64] = hc[bidx * HSZ + t + 64];
    __syncthreads();
    {
        float a = b1[t];
#pragma unroll 8
        for (int k = 0; k < HSZ; ++k) a += W1[t * HSZ + k] * hs[k];
        o1[t] = fmaxf(a, 0.0f);
    }
    __syncthreads();
    if (t < 32) {
        float a = b2[t];
#pragma unroll 8
        for (int k = 0; k < 64; ++k) a += W2[t * 64 + k] * o1[k];
        o2[t] = fmaxf(a, 0.0f);
    }
    __syncthreads();
    if (t < 4) {
        float a = b3[t];
#pragma unroll
        for (int k = 0; k < 32; ++k) a += W3[t * 32 + k] * o2[k];
        out[bidx * 4 + t] = a;
    }
}

// ---------------------------------------------------------------------------
extern "C" void kernel_launch(void* const* d_in, const int* in_sizes, int n_in,
                              void* d_out, int out_size, void* d_ws, size_t ws_size,
                              hipStream_t stream) {
    const float* x   = (const float*)d_in[0];
    const float* Wih = (const float*)d_in[1];
    const float* Whh = (const float*)d_in[2];
    const float* bih = (const float*)d_in[3];
    const float* bhh = (const float*)d_in[4];
    const float* W1  = (const float*)d_in[5];
    const float* b1  = (const float*)d_in[6];
    const float* W2  = (const float*)d_in[7];
    const float* b2  = (const float*)d_in[8];
    const float* W3  = (const float*)d_in[9];
    const float* b3  = (const float*)d_in[10];
    float* out = (float*)d_out;

    float* gx = (float*)d_ws;                          // TC*256*512 floats = 33.5 MB
    float* hc = gx + (size_t)TC * BATCH * G4;          // h then c: 2 * 256*128 floats

    for (int cidx = 0; cidx < NCHUNK; ++cidx) {
        gemm_gx_kernel<<<dim3(128, 4), 256, 0, stream>>>(x, Wih, bih, bhh, gx, cidx * TC);
        lstm_chunk_kernel<<<dim3(BATCH), 512, 0, stream>>>(gx, Whh, hc, cidx == 0);
    }
    head_kernel<<<dim3(BATCH), 64, 0, stream>>>(hc, W1, b1, W2, b2, W3, b3, out);
}

// Round 2
// 1371.184 us; speedup vs baseline: 1.0992x; 1.0992x over previous
//
#include <hip/hip_runtime.h>

// LSTM: B=256, T=512, I=256, H=128 (4H=512 gates), then MLP 128->64->32->4.
//   gemm_gx_kernel : gx[t_l*256+b][g] = x[b][t0+t_l][:] . W_ih[g][:] + bias  (fp32 tiled)
//   lstm_chunk_kernel : 1 block (1024 thr) per batch row. Thread (j,q), tid=j*8+q:
//       computes all 4 gates of hidden unit j over K-slice [16q,16q+16).
//       W in 64 VGPRs/thread, h broadcast from LDS (4 ds_read_b128/thread/step),
//       shfl_xor reduce over q, ONE barrier/step, gx folded into acc init (prefetched).
//   head_kernel : tiny MLP per row.

#define TC    64
#define NCHUNK 8
#define BATCH 256
#define TSEQ  512
#define ISZ   256
#define HSZ   128
#define G4    512

__device__ __forceinline__ float sigmoidf_(float x) {
    return 1.0f / (1.0f + __expf(-x));
}
__device__ __forceinline__ float tanhf_(float x) {
    float e = __expf(2.0f * x);          // saturates correctly for large |x|
    return 1.0f - 2.0f / (e + 1.0f);
}
__device__ __forceinline__ void fma4(float& a, const float4& w, const float4& h) {
    a += w.x * h.x; a += w.y * h.y; a += w.z * h.z; a += w.w * h.w;
}

// ---------------------------------------------------------------------------
// gx GEMM: M = TC*256 rows (m = t_l*256 + b), N = 512, K = 256, fp32.
__global__ __launch_bounds__(256, 2) void gemm_gx_kernel(
    const float* __restrict__ x, const float* __restrict__ Wih,
    const float* __restrict__ bih, const float* __restrict__ bhh,
    float* __restrict__ gx, int t0)
{
    __shared__ __align__(16) float As[128 * 36];
    __shared__ __align__(16) float Bs[128 * 36];
    const int tid   = threadIdx.x;
    const int mtile = blockIdx.x;          // 0..127
    const int ntile = blockIdx.y;          // 0..3
    const int tl = mtile >> 1;
    const int b0 = (mtile & 1) * 128;
    const int n0 = ntile * 128;
    const int tx = tid & 15;
    const int ty = tid >> 4;

    float acc[8][8];
#pragma unroll
    for (int i = 0; i < 8; ++i)
#pragma unroll
        for (int j = 0; j < 8; ++j) acc[i][j] = 0.0f;

    const int sf = tid & 7;
    const int sr = tid >> 3;

    for (int ks = 0; ks < ISZ; ks += 32) {
#pragma unroll
        for (int u = 0; u < 4; ++u) {
            const int r = sr + u * 32;
            const float4 va = *(const float4*)(
                x + ((size_t)(b0 + r) * TSEQ + (size_t)(t0 + tl)) * ISZ + ks + sf * 4);
            *(float4*)(&As[r * 36 + sf * 4]) = va;
            const float4 vb = *(const float4*)(
                Wih + (size_t)(n0 + r) * ISZ + ks + sf * 4);
            *(float4*)(&Bs[r * 36 + sf * 4]) = vb;
        }
        __syncthreads();
#pragma unroll
        for (int kq = 0; kq < 8; ++kq) {
            float4 av[8], bv[8];
#pragma unroll
            for (int i = 0; i < 8; ++i)
                av[i] = *(const float4*)(&As[(ty * 8 + i) * 36 + kq * 4]);
#pragma unroll
            for (int j = 0; j < 8; ++j)
                bv[j] = *(const float4*)(&Bs[(tx + 16 * j) * 36 + kq * 4]);
#pragma unroll
            for (int i = 0; i < 8; ++i)
#pragma unroll
                for (int j = 0; j < 8; ++j)
                    fma4(acc[i][j], av[i], bv[j]);
        }
        __syncthreads();
    }

    const int m0 = mtile * 128;
#pragma unroll
    for (int j = 0; j < 8; ++j) {
        const int n = n0 + tx + 16 * j;
        const float bias = bih[n] + bhh[n];
#pragma unroll
        for (int i = 0; i < 8; ++i) {
            const int r = ty * 8 + i;
            gx[(size_t)(m0 + r) * G4 + n] = acc[i][j] + bias;
        }
    }
}

// ---------------------------------------------------------------------------
// Recurrence. Grid = 256 blocks (one batch row each), 1024 threads.
// tid = j*8 + q : j = hidden unit (0..127), q = K-slice (0..7), k in [16q,16q+16).
// Thread holds W_hh rows for gates {i,f,g,o} of unit j over its K-slice: 64 VGPRs.
// acc[g] initialized with gx (lane q==g holds gx[g*128+j]); shfl_xor(1,2,4) reduces
// over the 8 q-lanes; q==0 applies activations, keeps c in a register, writes h_s[j].
__global__ __launch_bounds__(1024, 4) void lstm_chunk_kernel(
    const float* __restrict__ gx, const float* __restrict__ Whh,
    float* __restrict__ hc, int first)
{
    __shared__ __align__(16) float h_s[HSZ];
    const int b   = blockIdx.x;
    const int tid = threadIdx.x;
    const int j   = tid >> 3;
    const int q   = tid & 7;

    // W registers: Wr[g][k4] = W_hh[g*128+j][16q + 4*k4 .. +4)
    float4 Wr[4][4];
#pragma unroll
    for (int g = 0; g < 4; ++g) {
        const float4* row = (const float4*)(Whh + ((size_t)(g * HSZ + j)) * HSZ + 16 * q);
#pragma unroll
        for (int k4 = 0; k4 < 4; ++k4) Wr[g][k4] = row[k4];
    }

    float c = 0.0f;
    if (q == 0) {
        float h0 = 0.0f;
        if (!first) {
            h0 = hc[b * HSZ + j];
            c  = hc[BATCH * HSZ + b * HSZ + j];
        }
        h_s[j] = h0;
    }

    // software-pipelined gx prefetch: lane q holds gx[q*128+j] (gate g = q) for q<4
    const float* gxp = gx + (size_t)b * G4 + (q & 3) * HSZ + j;
    float gxv = (q < 4) ? gxp[0] : 0.0f;

    __syncthreads();

    for (int t = 0; t < TC; ++t) {
        // h fragment for this K-slice (broadcast within lane groups)
        const float4* h4 = (const float4*)(h_s + 16 * q);
        float4 hr0 = h4[0], hr1 = h4[1], hr2 = h4[2], hr3 = h4[3];

        // init accumulators with the precomputed x-part (+bias), one gate per lane q<4
        float acc[4];
#pragma unroll
        for (int g = 0; g < 4; ++g) acc[g] = (q == g) ? gxv : 0.0f;

        // prefetch next step's gx
        if (t + 1 < TC && q < 4) gxv = gxp[(size_t)(t + 1) * BATCH * G4];

#pragma unroll
        for (int g = 0; g < 4; ++g) {
            fma4(acc[g], Wr[g][0], hr0);
            fma4(acc[g], Wr[g][1], hr1);
            fma4(acc[g], Wr[g][2], hr2);
            fma4(acc[g], Wr[g][3], hr3);
        }

        // reduce across the 8 q-lanes of this hidden unit
#pragma unroll
        for (int m = 1; m < 8; m <<= 1) {
#pragma unroll
            for (int g = 0; g < 4; ++g) acc[g] += __shfl_xor(acc[g], m);
        }

        __syncthreads();          // everyone done reading h_s from this step
        if (q == 0) {
            const float ig = sigmoidf_(acc[0]);
            const float fg = sigmoidf_(acc[1]);
            const float gg = tanhf_(acc[2]);
            const float og = sigmoidf_(acc[3]);
            c = fg * c + ig * gg;
            h_s[j] = og * tanhf_(c);
        }
        __syncthreads();          // h_s updated for next step
    }

    if (q == 0) {
        hc[b * HSZ + j]               = h_s[j];
        hc[BATCH * HSZ + b * HSZ + j] = c;
    }
}

// ---------------------------------------------------------------------------
// MLP head: one block (64 threads) per batch row.
__global__ __launch_bounds__(64) void head_kernel(
    const float* __restrict__ hc,
    const float* __restrict__ W1, const float* __restrict__ b1,
    const float* __restrict__ W2, const float* __restrict__ b2,
    const float* __restrict__ W3, const float* __restrict__ b3,
    float* __restrict__ out)
{
    __shared__ float hs[HSZ];
    __shared__ float o1[64];
    __shared__ float o2[32];
    const int bidx = blockIdx.x;
    const int t = threadIdx.x;
    hs[t]      = hc[bidx * HSZ + t];
    hs[t + 64] = hc[bidx * HSZ + t + 64];
    __syncthreads();
    {
        float a = b1[t];
#pragma unroll 8
        for (int k = 0; k < HSZ; ++k) a += W1[t * HSZ + k] * hs[k];
        o1[t] = fmaxf(a, 0.0f);
    }
    __syncthreads();
    if (t < 32) {
        float a = b2[t];
#pragma unroll 8
        for (int k = 0; k < 64; ++k) a += W2[t * 64 + k] * o1[k];
        o2[t] = fmaxf(a, 0.0f);
    }
    __syncthreads();
    if (t < 4) {
        float a = b3[t];
#pragma unroll
        for (int k = 0; k < 32; ++k) a += W3[t * 32 + k] * o2[k];
        out[bidx * 4 + t] = a;
    }
}

// ---------------------------------------------------------------------------
extern "C" void kernel_launch(void* const* d_in, const int* in_sizes, int n_in,
                              void* d_out, int out_size, void* d_ws, size_t ws_size,
                              hipStream_t stream) {
    const float* x   = (const float*)d_in[0];
    const float* Wih = (const float*)d_in[1];
    const float* Whh = (const float*)d_in[2];
    const float* bih = (const float*)d_in[3];
    const float* bhh = (const float*)d_in[4];
    const float* W1  = (const float*)d_in[5];
    const float* b1  = (const float*)d_in[6];
    const float* W2  = (const float*)d_in[7];
    const float* b2  = (const float*)d_in[8];
    const float* W3  = (const float*)d_in[9];
    const float* b3  = (const float*)d_in[10];
    float* out = (float*)d_out;

    float* gx = (float*)d_ws;                          // TC*256*512 floats = 33.5 MB
    float* hc = gx + (size_t)TC * BATCH * G4;          // h then c: 2 * 256*128 floats

    for (int cidx = 0; cidx < NCHUNK; ++cidx) {
        gemm_gx_kernel<<<dim3(128, 4), 256, 0, stream>>>(x, Wih, bih, bhh, gx, cidx * TC);
        lstm_chunk_kernel<<<dim3(BATCH), 1024, 0, stream>>>(gx, Whh, hc, cidx == 0);
    }
    head_kernel<<<dim3(BATCH), 64, 0, stream>>>(hc, W1, b1, W2, b2, W3, b3, out);
}